// Round 5
// baseline (195.304 us; speedup 1.0000x reference)
//
#include <hip/hip_runtime.h>
#include <hip/hip_bf16.h>

typedef __hip_bfloat16 bf16;
typedef unsigned short u16;
typedef unsigned int u32;
typedef __attribute__((ext_vector_type(8))) short bf16x8;
typedef __attribute__((ext_vector_type(4))) float f32x4;

#define BB 4
#define CCH 32
#define HH 64
#define WW 64
#define NN 4096
#define D 288
#define DR 144
#define DQ 432
#define NH 8
#define HD 18
#define SPLIT 4
#define CHUNK 1024
#define NKSL 4
#define KS 256
#define DH 72
#define SCALE_ 0.16666666666666666f
#define QSCALE 0.24044917348149343f   // SCALE_ * log2(e)
#define EPS_ 1e-5f
#define ASTR 160
#define ATS 168
#define HSTR 96

__device__ __attribute__((aligned(16))) u16 g_Wcb[DQ * D];
__device__ __attribute__((aligned(16))) u16 g_pw[D * ASTR];
__device__ __attribute__((aligned(16))) u16 g_f1w[HSTR * D];
__device__ __attribute__((aligned(16))) u16 g_f2w[D * HSTR];
__device__ __attribute__((aligned(16))) u16 g_q[(size_t)BB * NH * NN * 32];
__device__ __attribute__((aligned(16))) u16 g_k[(size_t)BB * NH * NN * 32];
__device__ __attribute__((aligned(16))) u16 g_vt[(size_t)BB * NH * SPLIT * 32 * CHUNK];
__device__ __attribute__((aligned(16))) float g_part[NKSL * (size_t)BB * NH * NN * 20];
__device__ __attribute__((aligned(16))) u16 g_t0[(size_t)BB * NN * D];
__device__ __attribute__((aligned(16))) u16 g_t2b[(size_t)BB * D * NN];
__device__ int   g_flag;

__device__ __forceinline__ float b2f(bf16 v) { return __bfloat162float(v); }
__device__ __forceinline__ float bits2f(u16 u) { return __uint_as_float(((u32)u) << 16); }
__device__ __forceinline__ u16 f2bits(float f) {
    u32 u = __float_as_uint(f);
    return (u16)((u + 0x7FFF + ((u >> 16) & 1)) >> 16);
}
__device__ __forceinline__ float ldin(const void* p, size_t i, int isbf) {
    return isbf ? b2f(((const bf16*)p)[i]) : ((const float*)p)[i];
}
// pack exp2(e0), exp2(e1) as two truncated bf16 into one u32 (e0 = low half).
// raw v_exp_f32 (no OCML denorm-range fixup): S values are bounded (|S| << 126).
__device__ __forceinline__ u32 packexp(float e0, float e1) {
    float p0 = __builtin_amdgcn_exp2f(e0);
    float p1 = __builtin_amdgcn_exp2f(e1);
    return __builtin_amdgcn_perm(__float_as_uint(p1), __float_as_uint(p0), 0x07060302u);
}

#define RS  (D * ASTR + HSTR * D + D * HSTR)
#define RS2 (RS + BB * NH * SPLIT * CHUNK)
#define RSB ((RS2 + 255) / 256)
#define PATCHB (BB * HH)

// ---- prep: dtype detect + Wc GEMM + weight staging + vt ones row + patch extract
__global__ void k_prep(const void* __restrict__ x, const void* __restrict__ qkv_w,
                       const void* __restrict__ reduce_w, const void* __restrict__ proj_w,
                       const void* __restrict__ fc1_w, const void* __restrict__ fc2_w) {
    __shared__ int cnt4[4];
    __shared__ float qw[DR];
    __shared__ float slab[32 * 3 * 66];
    int tid = threadIdx.x;
    {
        const u16* u = (const u16*)x;
        int c = 0;
        for (int i = tid; i < 2048; i += 256) c += (((u[i] >> 7) & 0xFF) >= 0x90);
        for (int o = 32; o; o >>= 1) c += __shfl_xor(c, o);
        if ((tid & 63) == 0) cnt4[tid >> 6] = c;
    }
    __syncthreads();
    int bf = (cnt4[0] + cnt4[1] + cnt4[2] + cnt4[3]) < 32;
    if (tid == 0 && blockIdx.x == 0) g_flag = bf;

    int bid = blockIdx.x;
    if (bid < DQ) {
        int o = bid;
        if (tid < DR) qw[tid] = ldin(qkv_w, (size_t)o * DR + tid, bf);
        __syncthreads();
        for (int col = tid; col < D; col += 256) {
            float s0 = 0.f, s1 = 0.f;
            #pragma unroll 4
            for (int j = 0; j < DR; j += 2) {
                s0 += qw[j] * ldin(reduce_w, (size_t)j * D + col, bf);
                s1 += qw[j + 1] * ldin(reduce_w, (size_t)(j + 1) * D + col, bf);
            }
            g_Wcb[(size_t)o * D + col] = f2bits(s0 + s1);
        }
    } else if (bid < DQ + RSB) {
        int idx = (bid - DQ) * 256 + tid;
        if (idx < D * ASTR) {
            int o = idx / ASTR, j = idx % ASTR;
            g_pw[idx] = (j < DR) ? f2bits(ldin(proj_w, (size_t)o * DR + j, bf)) : (u16)0;
        } else if (idx < D * ASTR + HSTR * D) {
            int t = idx - D * ASTR;
            int o = t / D;
            g_f1w[t] = (o < DH) ? f2bits(ldin(fc1_w, (size_t)t, bf)) : (u16)0;
        } else if (idx < RS) {
            int t = idx - D * ASTR - HSTR * D;
            int o = t / HSTR, j = t % HSTR;
            g_f2w[t] = (j < DH) ? f2bits(ldin(fc2_w, (size_t)o * DH + j, bf)) : (u16)0;
        } else if (idx < RS2) {
            int t = idx - RS;
            int bhs = t >> 10, n = t & 1023;
            g_vt[((size_t)bhs * 32 + 18) * CHUNK + n] = 0x3F80;  // bf16 1.0
        }
    } else {
        int pb = bid - DQ - RSB;
        int b = pb >> 6, y = pb & 63;
        for (int idx = tid; idx < 32 * 3 * 66; idx += 256) {
            int c = idx / 198, rem = idx % 198;
            int ki = rem / 66, col = rem % 66 - 1;
            int sy = y + ki - 1;
            float v = 0.f;
            if (col >= 0 && col < 64 && sy >= 0 && sy < 64)
                v = ldin(x, ((size_t)(b * CCH + c) * HH + sy) * WW + col, bf);
            slab[idx] = v;
        }
        __syncthreads();
        size_t obase = ((size_t)b * NN + y * 64) * D;
        for (int idx = tid; idx < 64 * D; idx += 256) {
            int t = idx / D, f = idx % D;
            int c = f / 9, k = f % 9, ki = k / 3, kj = k % 3;
            g_t0[obase + idx] = f2bits(slab[c * 198 + ki * 66 + t + kj]);
        }
    }
}

// ---- LN1 + qkv GEMM; block = 32 tokens, dual A-tiles per B-load
__global__ void k_ln_qkv(const void* __restrict__ lnw, const void* __restrict__ lnb) {
    __shared__ __attribute__((aligned(16))) u16 xln[32 * 296];
    __shared__ float lnwf[D], lnbf[D];
    __shared__ float smu[32], srs[32];
    __shared__ u16 buf[3][144][32];
    int bf = g_flag;
    int tid = threadIdx.x;
    size_t tok0 = (size_t)blockIdx.x * 32;
    for (int i = tid; i < D; i += 256) { lnwf[i] = ldin(lnw, i, bf); lnbf[i] = ldin(lnb, i, bf); }
    {
        int tt = tid >> 3, p = tid & 7;
        const u32* pr = (const u32*)(g_t0 + (tok0 + tt) * D + p * 36);
        float s = 0.f, q = 0.f;
        #pragma unroll
        for (int j = 0; j < 18; ++j) {
            u32 v = pr[j];
            float a = bits2f((u16)(v & 0xFFFF)), b = bits2f((u16)(v >> 16));
            s += a + b; q += a * a + b * b;
        }
        #pragma unroll
        for (int o = 1; o < 8; o <<= 1) { s += __shfl_xor(s, o); q += __shfl_xor(q, o); }
        if (p == 0) {
            float mu = s / D;
            smu[tt] = mu;
            srs[tt] = rsqrtf(q / D - mu * mu + EPS_);
        }
    }
    __syncthreads();
    for (int idx = tid; idx < 32 * 144; idx += 256) {
        int t = idx / 144, dw = idx % 144;
        u32 v = *(const u32*)(g_t0 + (tok0 + t) * D + 2 * dw);
        float mu = smu[t], rs = srs[t];
        int f = 2 * dw;
        float a = (bits2f((u16)(v & 0xFFFF)) - mu) * rs * lnwf[f] + lnbf[f];
        float b = (bits2f((u16)(v >> 16)) - mu) * rs * lnwf[f + 1] + lnbf[f + 1];
        *(u32*)&xln[t * 296 + f] = (u32)f2bits(a) | ((u32)f2bits(b) << 16);
    }
    __syncthreads();
    int w = tid >> 6, lane = tid & 63, quad = lane >> 4, l15 = lane & 15;
    bf16x8 areg0[9], areg1[9];
    {
        const u16* a0 = xln + l15 * 296 + quad * 8;
        const u16* a1 = xln + (16 + l15) * 296 + quad * 8;
        #pragma unroll
        for (int ks = 0; ks < 9; ++ks) {
            areg0[ks] = *(const bf16x8*)(a0 + ks * 32);
            areg1[ks] = *(const bf16x8*)(a1 + ks * 32);
        }
    }
    int nt0 = w * 7, nt1 = (nt0 + 7 > 27) ? 27 : nt0 + 7;
    for (int nt = nt0; nt < nt1; ++nt) {
        f32x4 acc0 = {0.f, 0.f, 0.f, 0.f}, acc1 = {0.f, 0.f, 0.f, 0.f};
        const u16* bbase = g_Wcb + (size_t)(nt * 16 + l15) * D + quad * 8;
        #pragma unroll
        for (int ks = 0; ks < 9; ++ks) {
            bf16x8 bfr = *(const bf16x8*)(bbase + ks * 32);
            acc0 = __builtin_amdgcn_mfma_f32_16x16x32_bf16(areg0[ks], bfr, acc0, 0, 0, 0);
            acc1 = __builtin_amdgcn_mfma_f32_16x16x32_bf16(areg1[ks], bfr, acc1, 0, 0, 0);
        }
        int o = nt * 16 + l15;
        int which = o / DR, rem = o % DR;
        #pragma unroll
        for (int r = 0; r < 4; ++r) {
            buf[which][rem][quad * 4 + r] = f2bits(which == 0 ? acc0[r] * QSCALE : acc0[r]);
            buf[which][rem][16 + quad * 4 + r] = f2bits(which == 0 ? acc1[r] * QSCALE : acc1[r]);
        }
    }
    __syncthreads();
    {
        int b_ = (int)(tok0 >> 12);
        int n0 = (int)(tok0 & 4095);
        int sIdx = n0 >> 10, nc = n0 & 1023;
        for (int idx = tid; idx < 2 * 8 * 32 * 9; idx += 256) {
            int which = idx / 2304;
            int r2 = idx - which * 2304;
            int h = r2 / 288, r3 = r2 % 288, t = r3 / 9, dw = r3 % 9;
            u32 lo = buf[which][h * 18 + 2 * dw][t];
            u32 hi = buf[which][h * 18 + 2 * dw + 1][t];
            u16* dst = (which ? g_k : g_q) + ((size_t)(b_ * NH + h) * NN + n0 + t) * 32 + 2 * dw;
            *(u32*)dst = lo | (hi << 16);
        }
        // V^T store with the within-32 key permutation matching the register-resident
        // P fragment layout of the swapped-QK^T attention:
        //   pos(k) = 8*((k>>2)&3) + 4*(k>>4) + (k&3)   (bijection on [0,32))
        for (int idx = tid; idx < 144 * 16; idx += 256) {
            int rem = idx >> 4, tp = idx & 15;
            int hh = rem / HD, dd = rem % HD;
            u32 lo = buf[2][rem][2 * tp];
            u32 hi = buf[2][rem][2 * tp + 1];
            int k2 = 2 * tp;
            int pos = 8 * ((k2 >> 2) & 3) + 4 * (k2 >> 4) + (k2 & 3);
            size_t voff = (((size_t)(b_ * NH + hh) * SPLIT + sIdx) * 32 + dd) * CHUNK + nc + pos;
            *(u32*)&g_vt[voff] = lo | (hi << 16);
        }
    }
}

// ---- MFMA flash attention, 4-way split-K, LDS-free, K-prefetch software pipeline.
//      launch_bounds(128,4): ~120 regs live incl. K double-buffer — 8 waves/SIMD
//      would spill (round-2 evidence). K-only prefetch keeps budget under 128.
__global__ __launch_bounds__(128, 4) void k_attn() {
    int bid = blockIdx.x;
    int chunk = bid & 127;
    int qblk = (bid >> 7) & 7;
    int ksl = bid >> 10;                 // 0..3
    int s = chunk & 3, bh = chunk >> 2;
    int tid = threadIdx.x;
    int w = tid >> 6, lane = tid & 63, quad = lane >> 4, l15 = lane & 15;

    size_t rowbase = (size_t)bh * NN + s * CHUNK;
    size_t vtbase = ((size_t)bh * SPLIT + s) * 32 * CHUNK;
    const u16* kbase = g_k + rowbase * 32 + quad * 8;
    const u16* vbase = g_vt + vtbase + quad * 8;

    int qbase = qblk * 128 + w * 64;
    bf16x8 qf[4];
    #pragma unroll
    for (int t = 0; t < 4; ++t)
        qf[t] = *(const bf16x8*)(g_q + (rowbase + qbase + t * 16 + l15) * 32 + quad * 8);

    f32x4 accA[4], accB[4];
    #pragma unroll
    for (int t = 0; t < 4; ++t) {
        accA[t] = (f32x4){0.f, 0.f, 0.f, 0.f};
        accB[t] = (f32x4){0.f, 0.f, 0.f, 0.f};
    }

    int kt0 = ksl * KS;

    auto loadK = [&](bf16x8 (&dst)[4], int kt) {
        dst[0] = *(const bf16x8*)(kbase + (size_t)(kt + l15) * 32);
        dst[1] = *(const bf16x8*)(kbase + (size_t)(kt + 16 + l15) * 32);
        dst[2] = *(const bf16x8*)(kbase + (size_t)(kt + 32 + l15) * 32);
        dst[3] = *(const bf16x8*)(kbase + (size_t)(kt + 48 + l15) * 32);
    };
    // one 64-key step: V loads for this step issue first, then the NEXT step's K
    // loads (prefetch), then compute — the ~900-cyc compute hides the K latency.
    auto body = [&](bf16x8 (&kc)[4], bf16x8 (&kn)[4], int kt, bool pf) {
        bf16x8 vA0 = *(const bf16x8*)(vbase + (size_t)l15 * CHUNK + kt);
        bf16x8 vB0 = *(const bf16x8*)(vbase + (size_t)(16 + l15) * CHUNK + kt);
        bf16x8 vA1 = *(const bf16x8*)(vbase + (size_t)l15 * CHUNK + kt + 32);
        bf16x8 vB1 = *(const bf16x8*)(vbase + (size_t)(16 + l15) * CHUNK + kt + 32);
        if (pf) loadK(kn, kt + 64);
        f32x4 z = {0.f, 0.f, 0.f, 0.f};
        #pragma unroll
        for (int t = 0; t < 4; ++t) {
            __builtin_amdgcn_s_setprio(1);
            f32x4 S0 = __builtin_amdgcn_mfma_f32_16x16x32_bf16(kc[0], qf[t], z, 0, 0, 0);
            f32x4 S1 = __builtin_amdgcn_mfma_f32_16x16x32_bf16(kc[1], qf[t], z, 0, 0, 0);
            f32x4 S2 = __builtin_amdgcn_mfma_f32_16x16x32_bf16(kc[2], qf[t], z, 0, 0, 0);
            f32x4 S3 = __builtin_amdgcn_mfma_f32_16x16x32_bf16(kc[3], qf[t], z, 0, 0, 0);
            __builtin_amdgcn_s_setprio(0);
            union { u32 u[4]; bf16x8 v; } pa0, pa1;
            pa0.u[0] = packexp(S0[0], S0[1]);
            pa0.u[1] = packexp(S0[2], S0[3]);
            pa0.u[2] = packexp(S1[0], S1[1]);
            pa0.u[3] = packexp(S1[2], S1[3]);
            pa1.u[0] = packexp(S2[0], S2[1]);
            pa1.u[1] = packexp(S2[2], S2[3]);
            pa1.u[2] = packexp(S3[0], S3[1]);
            pa1.u[3] = packexp(S3[2], S3[3]);
            __builtin_amdgcn_s_setprio(1);
            accA[t] = __builtin_amdgcn_mfma_f32_16x16x32_bf16(pa0.v, vA0, accA[t], 0, 0, 0);
            accB[t] = __builtin_amdgcn_mfma_f32_16x16x32_bf16(pa0.v, vB0, accB[t], 0, 0, 0);
            accA[t] = __builtin_amdgcn_mfma_f32_16x16x32_bf16(pa1.v, vA1, accA[t], 0, 0, 0);
            accB[t] = __builtin_amdgcn_mfma_f32_16x16x32_bf16(pa1.v, vB1, accB[t], 0, 0, 0);
            __builtin_amdgcn_s_setprio(0);
        }
    };

    bf16x8 ka[4], kb[4];
    loadK(ka, kt0);
    body(ka, kb, kt0, true);
    body(kb, ka, kt0 + 64, true);
    body(ka, kb, kt0 + 128, true);
    body(kb, ka, kt0 + 192, false);

    float* pb = g_part + (((size_t)ksl * 32 + bh) * SPLIT + s) * (size_t)(CHUNK * 20);
    #pragma unroll
    for (int t = 0; t < 4; ++t) {
        #pragma unroll
        for (int r = 0; r < 4; ++r) {
            int tokenc = qbase + t * 16 + quad * 4 + r;
            float* row = pb + (size_t)tokenc * 20;
            row[l15] = accA[t][r];
            if (l15 < 3) row[16 + l15] = accB[t][r];
        }
    }
}

// ---- fused combine + proj + residual + LN2 + fc1 + relu + fc2 + residual
__global__ void k_proj_mlp(const void* __restrict__ proj_b, const void* __restrict__ lnw,
                           const void* __restrict__ lnb, const void* __restrict__ fc1_b,
                           const void* __restrict__ fc2_b) {
    __shared__ __attribute__((aligned(16))) u16 t1f[32 * 296];   // bf16 t1 tile
    __shared__ __attribute__((aligned(16))) u16 xln[32 * 296];   // LN2 out, reused for t2 stage
    __shared__ __attribute__((aligned(16))) u16 attnT[32 * ATS];
    __shared__ __attribute__((aligned(16))) u16 hbuf[32 * HSTR];
    __shared__ float lnwf[D], lnbf[D];
    __shared__ float smu[32], srs[32];
    int bf = g_flag;
    int tid = threadIdx.x;
    size_t tok0 = (size_t)blockIdx.x * 32;
    int w = tid >> 6, lane = tid & 63, quad = lane >> 4, l15 = lane & 15;
    for (int i = tid; i < D; i += 256) { lnwf[i] = ldin(lnw, i, bf); lnbf[i] = ldin(lnb, i, bf); }

    // phase 0: 4-way split-K combine -> attnT
    int b_ = (int)(tok0 >> 12);
    int s_ = ((int)tok0 & 4095) >> 10;
    int tc0 = (int)tok0 & 1023;
    for (int idx = tid; idx < 32 * (ATS - DR); idx += 256) {
        int t = idx / (ATS - DR), f = idx % (ATS - DR);
        attnT[t * ATS + DR + f] = 0;
    }
    {
        int t = tid >> 3, h = tid & 7;
        const float* p1 = g_part + (((size_t)(b_ * NH + h)) * SPLIT + s_) * (size_t)(CHUNK * 20)
                        + (size_t)(tc0 + t) * 20;
        const size_t SL = (size_t)32 * SPLIT * CHUNK * 20;
        f32x4 a0 = {0,0,0,0}, a1 = {0,0,0,0}, a2 = {0,0,0,0}, a3 = {0,0,0,0}, a4 = {0,0,0,0};
        #pragma unroll
        for (int sl = 0; sl < NKSL; ++sl) {
            const float* p = p1 + sl * SL;
            a0 += *(const f32x4*)p;
            a1 += *(const f32x4*)(p + 4);
            a2 += *(const f32x4*)(p + 8);
            a3 += *(const f32x4*)(p + 12);
            a4 += *(const f32x4*)(p + 16);
        }
        float inv = 1.f / a4[2];
        u16* dst = attnT + t * ATS + h * HD;
        #pragma unroll
        for (int d = 0; d < 4; ++d) {
            dst[d]      = f2bits(a0[d] * inv);
            dst[4 + d]  = f2bits(a1[d] * inv);
            dst[8 + d]  = f2bits(a2[d] * inv);
            dst[12 + d] = f2bits(a3[d] * inv);
        }
        dst[16] = f2bits(a4[0] * inv);
        dst[17] = f2bits(a4[1] * inv);
    }
    __syncthreads();

    // phase A: proj + residual -> t1f (LDS only)
    {
        bf16x8 areg0[5], areg1[5];
        const u16* a0 = attnT + l15 * ATS + quad * 8;
        const u16* a1 = attnT + (16 + l15) * ATS + quad * 8;
        #pragma unroll
        for (int ks = 0; ks < 5; ++ks) {
            areg0[ks] = *(const bf16x8*)(a0 + ks * 32);
            areg1[ks] = *(const bf16x8*)(a1 + ks * 32);
        }
        const int tab[5] = {0, 5, 10, 14, 18};
        for (int nt = tab[w]; nt < tab[w + 1]; ++nt) {
            f32x4 acc0 = {0.f, 0.f, 0.f, 0.f}, acc1 = {0.f, 0.f, 0.f, 0.f};
            const u16* bbase = g_pw + (size_t)(nt * 16 + l15) * ASTR + quad * 8;
            #pragma unroll
            for (int ks = 0; ks < 5; ++ks) {
                bf16x8 bfr = *(const bf16x8*)(bbase + ks * 32);
                acc0 = __builtin_amdgcn_mfma_f32_16x16x32_bf16(areg0[ks], bfr, acc0, 0, 0, 0);
                acc1 = __builtin_amdgcn_mfma_f32_16x16x32_bf16(areg1[ks], bfr, acc1, 0, 0, 0);
            }
            int o = nt * 16 + l15;
            float bias = ldin(proj_b, o, bf);
            #pragma unroll
            for (int r = 0; r < 4; ++r) {
                t1f[(quad * 4 + r) * 296 + o] =
                    f2bits(bits2f(g_t0[(tok0 + quad * 4 + r) * D + o]) + acc0[r] + bias);
                t1f[(16 + quad * 4 + r) * 296 + o] =
                    f2bits(bits2f(g_t0[(tok0 + 16 + quad * 4 + r) * D + o]) + acc1[r] + bias);
            }
        }
    }
    __syncthreads();
    {   // phase B: LN2 stats
        int tt = tid >> 3, p = tid & 7;
        const u32* src = (const u32*)&t1f[tt * 296 + p * 36];
        float s = 0.f, q = 0.f;
        #pragma unroll
        for (int j = 0; j < 18; ++j) {
            u32 v = src[j];
            float a = bits2f((u16)(v & 0xFFFF)), b = bits2f((u16)(v >> 16));
            s += a + b; q += a * a + b * b;
        }
        #pragma unroll
        for (int o = 1; o < 8; o <<= 1) { s += __shfl_xor(s, o); q += __shfl_xor(q, o); }
        if (p == 0) {
            float mu = s / D;
            smu[tt] = mu;
            srs[tt] = rsqrtf(q / D - mu * mu + EPS_);
        }
    }
    __syncthreads();
    for (int idx = tid; idx < 32 * 144; idx += 256) {   // phase C: normalize
        int t = idx / 144, dw = idx % 144;
        int f = 2 * dw;
        u32 v = *(const u32*)&t1f[t * 296 + f];
        float mu = smu[t], rs = srs[t];
        float a = (bits2f((u16)(v & 0xFFFF)) - mu) * rs * lnwf[f] + lnbf[f];
        float b = (bits2f((u16)(v >> 16)) - mu) * rs * lnwf[f + 1] + lnbf[f + 1];
        *(u32*)&xln[t * 296 + f] = (u32)f2bits(a) | ((u32)f2bits(b) << 16);
    }
    __syncthreads();
    {   // phase D: fc1 + relu -> hbuf (LDS)
        bf16x8 areg0[9], areg1[9];
        const u16* a0 = xln + l15 * 296 + quad * 8;
        const u16* a1 = xln + (16 + l15) * 296 + quad * 8;
        #pragma unroll
        for (int ks = 0; ks < 9; ++ks) {
            areg0[ks] = *(const bf16x8*)(a0 + ks * 32);
            areg1[ks] = *(const bf16x8*)(a1 + ks * 32);
        }
        const int tab2[5] = {0, 2, 4, 5, 6};
        for (int nt = tab2[w]; nt < tab2[w + 1]; ++nt) {
            f32x4 acc0 = {0.f, 0.f, 0.f, 0.f}, acc1 = {0.f, 0.f, 0.f, 0.f};
            const u16* bbase = g_f1w + (size_t)(nt * 16 + l15) * D + quad * 8;
            #pragma unroll
            for (int ks = 0; ks < 9; ++ks) {
                bf16x8 bfr = *(const bf16x8*)(bbase + ks * 32);
                acc0 = __builtin_amdgcn_mfma_f32_16x16x32_bf16(areg0[ks], bfr, acc0, 0, 0, 0);
                acc1 = __builtin_amdgcn_mfma_f32_16x16x32_bf16(areg1[ks], bfr, acc1, 0, 0, 0);
            }
            int o = nt * 16 + l15;
            float bias = (o < DH) ? ldin(fc1_b, o, bf) : 0.f;
            #pragma unroll
            for (int r = 0; r < 4; ++r) {
                hbuf[(quad * 4 + r) * HSTR + o] = f2bits(fmaxf(acc0[r] + bias, 0.f));
                hbuf[(16 + quad * 4 + r) * HSTR + o] = f2bits(fmaxf(acc1[r] + bias, 0.f));
            }
        }
    }
    __syncthreads();
    {   // phase E: fc2 + residual -> t2 bf16, staged in xln
        bf16x8 areg0[3], areg1[3];
        const u16* a0 = hbuf + l15 * HSTR + quad * 8;
        const u16* a1 = hbuf + (16 + l15) * HSTR + quad * 8;
        #pragma unroll
        for (int ks = 0; ks < 3; ++ks) {
            areg0[ks] = *(const bf16x8*)(a0 + ks * 32);
            areg1[ks] = *(const bf16x8*)(a1 + ks * 32);
        }
        const int tab[5] = {0, 5, 10, 14, 18};
        for (int nt = tab[w]; nt < tab[w + 1]; ++nt) {
            f32x4 acc0 = {0.f, 0.f, 0.f, 0.f}, acc1 = {0.f, 0.f, 0.f, 0.f};
            const u16* bbase = g_f2w + (size_t)(nt * 16 + l15) * HSTR + quad * 8;
            #pragma unroll
            for (int ks = 0; ks < 3; ++ks) {
                bf16x8 bfr = *(const bf16x8*)(bbase + ks * 32);
                acc0 = __builtin_amdgcn_mfma_f32_16x16x32_bf16(areg0[ks], bfr, acc0, 0, 0, 0);
                acc1 = __builtin_amdgcn_mfma_f32_16x16x32_bf16(areg1[ks], bfr, acc1, 0, 0, 0);
            }
            int o = nt * 16 + l15;
            float bias = ldin(fc2_b, o, bf);
            #pragma unroll
            for (int r = 0; r < 4; ++r) {
                xln[(quad * 4 + r) * 296 + o] =
                    f2bits(bits2f(t1f[(quad * 4 + r) * 296 + o]) + acc0[r] + bias);
                xln[(16 + quad * 4 + r) * 296 + o] =
                    f2bits(bits2f(t1f[(16 + quad * 4 + r) * 296 + o]) + acc1[r] + bias);
            }
        }
    }
    __syncthreads();
    {   // transposed u32-packed store to g_t2b
        int n0 = (int)(tok0 & 4095);
        for (int idx = tid; idx < D * 16; idx += 256) {
            int o = idx >> 4, tp = idx & 15;
            u32 v = (u32)xln[(2 * tp) * 296 + o] | ((u32)xln[(2 * tp + 1) * 296 + o] << 16);
            *(u32*)&g_t2b[((size_t)b_ * D + o) * NN + n0 + 2 * tp] = v;
        }
    }
}

// ---- fold -> out
__global__ void k_fold(void* __restrict__ out) {
    int bf = g_flag;
    int idx = blockIdx.x * blockDim.x + threadIdx.x;
    if (idx >= BB * CCH * HH * WW) return;
    int xx = idx % WW;
    int y = (idx / WW) % HH;
    int c = (idx / (WW * HH)) % CCH;
    int b = idx / (WW * HH * CCH);
    const u16* base = g_t2b + ((size_t)b * D + c * 9) * NN;
    float s = 0.f;
    #pragma unroll
    for (int i = 0; i < 3; ++i) {
        int sy = y + 1 - i;
        if (sy < 0 || sy >= HH) continue;
        #pragma unroll
        for (int j = 0; j < 3; ++j) {
            int sx = xx + 1 - j;
            if (sx < 0 || sx >= WW) continue;
            s += bits2f(base[(size_t)(i * 3 + j) * NN + sy * WW + sx]);
        }
    }
    if (bf) ((bf16*)out)[idx] = __float2bfloat16(s);
    else    ((float*)out)[idx] = s;
}

extern "C" void kernel_launch(void* const* d_in, const int* in_sizes, int n_in,
                              void* d_out, int out_size, void* d_ws, size_t ws_size,
                              hipStream_t stream) {
    const void* x        = d_in[0];
    const void* ln1_w    = d_in[1];
    const void* ln1_b    = d_in[2];
    const void* reduce_w = d_in[3];
    const void* qkv_w    = d_in[4];
    const void* proj_w   = d_in[5];
    const void* proj_b   = d_in[6];
    const void* ln2_w    = d_in[7];
    const void* ln2_b    = d_in[8];
    const void* fc1_w    = d_in[9];
    const void* fc1_b    = d_in[10];
    const void* fc2_w    = d_in[11];
    const void* fc2_b    = d_in[12];

    k_prep     <<<DQ + RSB + PATCHB, 256, 0, stream>>>(x, qkv_w, reduce_w, proj_w, fc1_w, fc2_w);
    k_ln_qkv   <<<BB * NN / 32, 256, 0, stream>>>(ln1_w, ln1_b);
    k_attn     <<<NKSL * BB * NH * SPLIT * 8, 128, 0, stream>>>();
    k_proj_mlp <<<BB * NN / 32, 256, 0, stream>>>(proj_b, ln2_w, ln2_b, fc1_b, fc2_b);
    k_fold     <<<(BB * CCH * HH * WW + 255) / 256, 256, 0, stream>>>(d_out);
}

// Round 6
// 187.939 us; speedup vs baseline: 1.0392x; 1.0392x over previous
//
#include <hip/hip_runtime.h>
#include <hip/hip_bf16.h>

typedef __hip_bfloat16 bf16;
typedef unsigned short u16;
typedef unsigned int u32;
typedef __attribute__((ext_vector_type(8))) short bf16x8;
typedef __attribute__((ext_vector_type(4))) float f32x4;

#define BB 4
#define CCH 32
#define HH 64
#define WW 64
#define NN 4096
#define D 288
#define DR 144
#define DQ 432
#define NH 8
#define HD 18
#define SPLIT 4
#define CHUNK 1024
#define NKSL 2
#define KS 512
#define DH 72
#define SCALE_ 0.16666666666666666f
#define QSCALE 0.24044917348149343f   // SCALE_ * log2(e)
#define EPS_ 1e-5f
#define ASTR 160
#define ATS 168
#define HSTR 96

__device__ __attribute__((aligned(16))) u16 g_Wcb[DQ * D];
__device__ __attribute__((aligned(16))) u16 g_pw[D * ASTR];
__device__ __attribute__((aligned(16))) u16 g_f1w[HSTR * D];
__device__ __attribute__((aligned(16))) u16 g_f2w[D * HSTR];
__device__ __attribute__((aligned(16))) u16 g_q[(size_t)BB * NH * NN * 32];
__device__ __attribute__((aligned(16))) u16 g_k[(size_t)BB * NH * NN * 32];
__device__ __attribute__((aligned(16))) u16 g_vt[(size_t)BB * NH * SPLIT * 32 * CHUNK];
__device__ __attribute__((aligned(16))) float g_part[NKSL * (size_t)BB * NH * NN * 20];
__device__ __attribute__((aligned(16))) u16 g_t0[(size_t)BB * NN * D];
__device__ __attribute__((aligned(16))) u16 g_t2b[(size_t)BB * D * NN];
__device__ int   g_flag;

__device__ __forceinline__ float b2f(bf16 v) { return __bfloat162float(v); }
__device__ __forceinline__ float bits2f(u16 u) { return __uint_as_float(((u32)u) << 16); }
__device__ __forceinline__ u16 f2bits(float f) {
    u32 u = __float_as_uint(f);
    return (u16)((u + 0x7FFF + ((u >> 16) & 1)) >> 16);
}
__device__ __forceinline__ float ldin(const void* p, size_t i, int isbf) {
    return isbf ? b2f(((const bf16*)p)[i]) : ((const float*)p)[i];
}
// pack exp2(e0), exp2(e1) as two truncated bf16 into one u32 (e0 = low half).
// raw v_exp_f32 (no OCML denorm-range fixup): S values are bounded (|S| << 126).
__device__ __forceinline__ u32 packexp(float e0, float e1) {
    float p0 = __builtin_amdgcn_exp2f(e0);
    float p1 = __builtin_amdgcn_exp2f(e1);
    return __builtin_amdgcn_perm(__float_as_uint(p1), __float_as_uint(p0), 0x07060302u);
}

#define RS  (D * ASTR + HSTR * D + D * HSTR)
#define RS2 (RS + BB * NH * SPLIT * CHUNK)
#define RSB ((RS2 + 255) / 256)
#define PATCHB (BB * HH)

// ---- prep: dtype detect + Wc GEMM + weight staging + vt ones row + patch extract
__global__ void k_prep(const void* __restrict__ x, const void* __restrict__ qkv_w,
                       const void* __restrict__ reduce_w, const void* __restrict__ proj_w,
                       const void* __restrict__ fc1_w, const void* __restrict__ fc2_w) {
    __shared__ int cnt4[4];
    __shared__ float qw[DR];
    __shared__ float slab[32 * 3 * 66];
    int tid = threadIdx.x;
    {
        const u16* u = (const u16*)x;
        int c = 0;
        for (int i = tid; i < 2048; i += 256) c += (((u[i] >> 7) & 0xFF) >= 0x90);
        for (int o = 32; o; o >>= 1) c += __shfl_xor(c, o);
        if ((tid & 63) == 0) cnt4[tid >> 6] = c;
    }
    __syncthreads();
    int bf = (cnt4[0] + cnt4[1] + cnt4[2] + cnt4[3]) < 32;
    if (tid == 0 && blockIdx.x == 0) g_flag = bf;

    int bid = blockIdx.x;
    if (bid < DQ) {
        int o = bid;
        if (tid < DR) qw[tid] = ldin(qkv_w, (size_t)o * DR + tid, bf);
        __syncthreads();
        for (int col = tid; col < D; col += 256) {
            float s0 = 0.f, s1 = 0.f;
            #pragma unroll 4
            for (int j = 0; j < DR; j += 2) {
                s0 += qw[j] * ldin(reduce_w, (size_t)j * D + col, bf);
                s1 += qw[j + 1] * ldin(reduce_w, (size_t)(j + 1) * D + col, bf);
            }
            g_Wcb[(size_t)o * D + col] = f2bits(s0 + s1);
        }
    } else if (bid < DQ + RSB) {
        int idx = (bid - DQ) * 256 + tid;
        if (idx < D * ASTR) {
            int o = idx / ASTR, j = idx % ASTR;
            g_pw[idx] = (j < DR) ? f2bits(ldin(proj_w, (size_t)o * DR + j, bf)) : (u16)0;
        } else if (idx < D * ASTR + HSTR * D) {
            int t = idx - D * ASTR;
            int o = t / D;
            g_f1w[t] = (o < DH) ? f2bits(ldin(fc1_w, (size_t)t, bf)) : (u16)0;
        } else if (idx < RS) {
            int t = idx - D * ASTR - HSTR * D;
            int o = t / HSTR, j = t % HSTR;
            g_f2w[t] = (j < DH) ? f2bits(ldin(fc2_w, (size_t)o * DH + j, bf)) : (u16)0;
        } else if (idx < RS2) {
            int t = idx - RS;
            int bhs = t >> 10, n = t & 1023;
            g_vt[((size_t)bhs * 32 + 18) * CHUNK + n] = 0x3F80;  // bf16 1.0
        }
    } else {
        int pb = bid - DQ - RSB;
        int b = pb >> 6, y = pb & 63;
        for (int idx = tid; idx < 32 * 3 * 66; idx += 256) {
            int c = idx / 198, rem = idx % 198;
            int ki = rem / 66, col = rem % 66 - 1;
            int sy = y + ki - 1;
            float v = 0.f;
            if (col >= 0 && col < 64 && sy >= 0 && sy < 64)
                v = ldin(x, ((size_t)(b * CCH + c) * HH + sy) * WW + col, bf);
            slab[idx] = v;
        }
        __syncthreads();
        size_t obase = ((size_t)b * NN + y * 64) * D;
        for (int idx = tid; idx < 64 * D; idx += 256) {
            int t = idx / D, f = idx % D;
            int c = f / 9, k = f % 9, ki = k / 3, kj = k % 3;
            g_t0[obase + idx] = f2bits(slab[c * 198 + ki * 66 + t + kj]);
        }
    }
}

// ---- LN1 + qkv GEMM; block = 32 tokens, dual A-tiles per B-load
__global__ void k_ln_qkv(const void* __restrict__ lnw, const void* __restrict__ lnb) {
    __shared__ __attribute__((aligned(16))) u16 xln[32 * 296];
    __shared__ float lnwf[D], lnbf[D];
    __shared__ float smu[32], srs[32];
    __shared__ u16 buf[3][144][32];
    int bf = g_flag;
    int tid = threadIdx.x;
    size_t tok0 = (size_t)blockIdx.x * 32;
    for (int i = tid; i < D; i += 256) { lnwf[i] = ldin(lnw, i, bf); lnbf[i] = ldin(lnb, i, bf); }
    {
        int tt = tid >> 3, p = tid & 7;
        const u32* pr = (const u32*)(g_t0 + (tok0 + tt) * D + p * 36);
        float s = 0.f, q = 0.f;
        #pragma unroll
        for (int j = 0; j < 18; ++j) {
            u32 v = pr[j];
            float a = bits2f((u16)(v & 0xFFFF)), b = bits2f((u16)(v >> 16));
            s += a + b; q += a * a + b * b;
        }
        #pragma unroll
        for (int o = 1; o < 8; o <<= 1) { s += __shfl_xor(s, o); q += __shfl_xor(q, o); }
        if (p == 0) {
            float mu = s / D;
            smu[tt] = mu;
            srs[tt] = rsqrtf(q / D - mu * mu + EPS_);
        }
    }
    __syncthreads();
    for (int idx = tid; idx < 32 * 144; idx += 256) {
        int t = idx / 144, dw = idx % 144;
        u32 v = *(const u32*)(g_t0 + (tok0 + t) * D + 2 * dw);
        float mu = smu[t], rs = srs[t];
        int f = 2 * dw;
        float a = (bits2f((u16)(v & 0xFFFF)) - mu) * rs * lnwf[f] + lnbf[f];
        float b = (bits2f((u16)(v >> 16)) - mu) * rs * lnwf[f + 1] + lnbf[f + 1];
        *(u32*)&xln[t * 296 + f] = (u32)f2bits(a) | ((u32)f2bits(b) << 16);
    }
    __syncthreads();
    int w = tid >> 6, lane = tid & 63, quad = lane >> 4, l15 = lane & 15;
    bf16x8 areg0[9], areg1[9];
    {
        const u16* a0 = xln + l15 * 296 + quad * 8;
        const u16* a1 = xln + (16 + l15) * 296 + quad * 8;
        #pragma unroll
        for (int ks = 0; ks < 9; ++ks) {
            areg0[ks] = *(const bf16x8*)(a0 + ks * 32);
            areg1[ks] = *(const bf16x8*)(a1 + ks * 32);
        }
    }
    int nt0 = w * 7, nt1 = (nt0 + 7 > 27) ? 27 : nt0 + 7;
    for (int nt = nt0; nt < nt1; ++nt) {
        f32x4 acc0 = {0.f, 0.f, 0.f, 0.f}, acc1 = {0.f, 0.f, 0.f, 0.f};
        const u16* bbase = g_Wcb + (size_t)(nt * 16 + l15) * D + quad * 8;
        #pragma unroll
        for (int ks = 0; ks < 9; ++ks) {
            bf16x8 bfr = *(const bf16x8*)(bbase + ks * 32);
            acc0 = __builtin_amdgcn_mfma_f32_16x16x32_bf16(areg0[ks], bfr, acc0, 0, 0, 0);
            acc1 = __builtin_amdgcn_mfma_f32_16x16x32_bf16(areg1[ks], bfr, acc1, 0, 0, 0);
        }
        int o = nt * 16 + l15;
        int which = o / DR, rem = o % DR;
        #pragma unroll
        for (int r = 0; r < 4; ++r) {
            buf[which][rem][quad * 4 + r] = f2bits(which == 0 ? acc0[r] * QSCALE : acc0[r]);
            buf[which][rem][16 + quad * 4 + r] = f2bits(which == 0 ? acc1[r] * QSCALE : acc1[r]);
        }
    }
    __syncthreads();
    {
        int b_ = (int)(tok0 >> 12);
        int n0 = (int)(tok0 & 4095);
        int sIdx = n0 >> 10, nc = n0 & 1023;
        for (int idx = tid; idx < 2 * 8 * 32 * 9; idx += 256) {
            int which = idx / 2304;
            int r2 = idx - which * 2304;
            int h = r2 / 288, r3 = r2 % 288, t = r3 / 9, dw = r3 % 9;
            u32 lo = buf[which][h * 18 + 2 * dw][t];
            u32 hi = buf[which][h * 18 + 2 * dw + 1][t];
            u16* dst = (which ? g_k : g_q) + ((size_t)(b_ * NH + h) * NN + n0 + t) * 32 + 2 * dw;
            *(u32*)dst = lo | (hi << 16);
        }
        // V^T store with the within-32 key permutation matching the register-resident
        // P fragment layout of the swapped-QK^T attention:
        //   pos(k) = 8*((k>>2)&3) + 4*(k>>4) + (k&3)   (bijection on [0,32))
        for (int idx = tid; idx < 144 * 16; idx += 256) {
            int rem = idx >> 4, tp = idx & 15;
            int hh = rem / HD, dd = rem % HD;
            u32 lo = buf[2][rem][2 * tp];
            u32 hi = buf[2][rem][2 * tp + 1];
            int k2 = 2 * tp;
            int pos = 8 * ((k2 >> 2) & 3) + 4 * (k2 >> 4) + (k2 & 3);
            size_t voff = (((size_t)(b_ * NH + hh) * SPLIT + sIdx) * 32 + dd) * CHUNK + nc + pos;
            *(u32*)&g_vt[voff] = lo | (hi << 16);
        }
    }
}

// ---- MFMA flash attention, 2-way split-K, LDS-free, K-prefetch software pipeline.
//      KS=512 -> 8 iterations/block: amortizes the exposed prologue (Q+K first-load
//      latency) that dominated the 4-iteration NKSL=4 variant; also halves g_part.
//      launch_bounds(128,4): ~100-120 regs live incl. K double-buffer; (128,8) spills.
__global__ __launch_bounds__(128, 4) void k_attn() {
    int bid = blockIdx.x;
    int chunk = bid & 127;
    int qblk = (bid >> 7) & 7;
    int ksl = bid >> 10;                 // 0..1
    int s = chunk & 3, bh = chunk >> 2;
    int tid = threadIdx.x;
    int w = tid >> 6, lane = tid & 63, quad = lane >> 4, l15 = lane & 15;

    size_t rowbase = (size_t)bh * NN + s * CHUNK;
    size_t vtbase = ((size_t)bh * SPLIT + s) * 32 * CHUNK;
    const u16* kbase = g_k + rowbase * 32 + quad * 8;
    const u16* vbase = g_vt + vtbase + quad * 8;

    int qbase = qblk * 128 + w * 64;
    bf16x8 qf[4];
    #pragma unroll
    for (int t = 0; t < 4; ++t)
        qf[t] = *(const bf16x8*)(g_q + (rowbase + qbase + t * 16 + l15) * 32 + quad * 8);

    f32x4 accA[4], accB[4];
    #pragma unroll
    for (int t = 0; t < 4; ++t) {
        accA[t] = (f32x4){0.f, 0.f, 0.f, 0.f};
        accB[t] = (f32x4){0.f, 0.f, 0.f, 0.f};
    }

    int kt0 = ksl * KS;

    auto loadK = [&](bf16x8 (&dst)[4], int kt) {
        dst[0] = *(const bf16x8*)(kbase + (size_t)(kt + l15) * 32);
        dst[1] = *(const bf16x8*)(kbase + (size_t)(kt + 16 + l15) * 32);
        dst[2] = *(const bf16x8*)(kbase + (size_t)(kt + 32 + l15) * 32);
        dst[3] = *(const bf16x8*)(kbase + (size_t)(kt + 48 + l15) * 32);
    };
    // one 64-key step: V loads for this step issue first (hidden under QK+exp),
    // then the NEXT step's K loads (prefetch), then compute.
    auto body = [&](bf16x8 (&kc)[4], bf16x8 (&kn)[4], int kt, bool pf) {
        bf16x8 vA0 = *(const bf16x8*)(vbase + (size_t)l15 * CHUNK + kt);
        bf16x8 vB0 = *(const bf16x8*)(vbase + (size_t)(16 + l15) * CHUNK + kt);
        bf16x8 vA1 = *(const bf16x8*)(vbase + (size_t)l15 * CHUNK + kt + 32);
        bf16x8 vB1 = *(const bf16x8*)(vbase + (size_t)(16 + l15) * CHUNK + kt + 32);
        if (pf) loadK(kn, kt + 64);
        f32x4 z = {0.f, 0.f, 0.f, 0.f};
        #pragma unroll
        for (int t = 0; t < 4; ++t) {
            __builtin_amdgcn_s_setprio(1);
            f32x4 S0 = __builtin_amdgcn_mfma_f32_16x16x32_bf16(kc[0], qf[t], z, 0, 0, 0);
            f32x4 S1 = __builtin_amdgcn_mfma_f32_16x16x32_bf16(kc[1], qf[t], z, 0, 0, 0);
            f32x4 S2 = __builtin_amdgcn_mfma_f32_16x16x32_bf16(kc[2], qf[t], z, 0, 0, 0);
            f32x4 S3 = __builtin_amdgcn_mfma_f32_16x16x32_bf16(kc[3], qf[t], z, 0, 0, 0);
            __builtin_amdgcn_s_setprio(0);
            union { u32 u[4]; bf16x8 v; } pa0, pa1;
            pa0.u[0] = packexp(S0[0], S0[1]);
            pa0.u[1] = packexp(S0[2], S0[3]);
            pa0.u[2] = packexp(S1[0], S1[1]);
            pa0.u[3] = packexp(S1[2], S1[3]);
            pa1.u[0] = packexp(S2[0], S2[1]);
            pa1.u[1] = packexp(S2[2], S2[3]);
            pa1.u[2] = packexp(S3[0], S3[1]);
            pa1.u[3] = packexp(S3[2], S3[3]);
            __builtin_amdgcn_s_setprio(1);
            accA[t] = __builtin_amdgcn_mfma_f32_16x16x32_bf16(pa0.v, vA0, accA[t], 0, 0, 0);
            accB[t] = __builtin_amdgcn_mfma_f32_16x16x32_bf16(pa0.v, vB0, accB[t], 0, 0, 0);
            accA[t] = __builtin_amdgcn_mfma_f32_16x16x32_bf16(pa1.v, vA1, accA[t], 0, 0, 0);
            accB[t] = __builtin_amdgcn_mfma_f32_16x16x32_bf16(pa1.v, vB1, accB[t], 0, 0, 0);
            __builtin_amdgcn_s_setprio(0);
        }
    };

    bf16x8 ka[4], kb[4];
    loadK(ka, kt0);
    #pragma unroll
    for (int it = 0; it < 4; ++it) {
        body(ka, kb, kt0 + it * 128, true);
        body(kb, ka, kt0 + it * 128 + 64, it < 3);
    }

    float* pb = g_part + (((size_t)ksl * 32 + bh) * SPLIT + s) * (size_t)(CHUNK * 20);
    #pragma unroll
    for (int t = 0; t < 4; ++t) {
        #pragma unroll
        for (int r = 0; r < 4; ++r) {
            int tokenc = qbase + t * 16 + quad * 4 + r;
            float* row = pb + (size_t)tokenc * 20;
            row[l15] = accA[t][r];
            if (l15 < 3) row[16 + l15] = accB[t][r];
        }
    }
}

// ---- fused combine + proj + residual + LN2 + fc1 + relu + fc2 + residual
__global__ void k_proj_mlp(const void* __restrict__ proj_b, const void* __restrict__ lnw,
                           const void* __restrict__ lnb, const void* __restrict__ fc1_b,
                           const void* __restrict__ fc2_b) {
    __shared__ __attribute__((aligned(16))) u16 t1f[32 * 296];   // bf16 t1 tile
    __shared__ __attribute__((aligned(16))) u16 xln[32 * 296];   // LN2 out, reused for t2 stage
    __shared__ __attribute__((aligned(16))) u16 attnT[32 * ATS];
    __shared__ __attribute__((aligned(16))) u16 hbuf[32 * HSTR];
    __shared__ float lnwf[D], lnbf[D];
    __shared__ float smu[32], srs[32];
    int bf = g_flag;
    int tid = threadIdx.x;
    size_t tok0 = (size_t)blockIdx.x * 32;
    int w = tid >> 6, lane = tid & 63, quad = lane >> 4, l15 = lane & 15;
    for (int i = tid; i < D; i += 256) { lnwf[i] = ldin(lnw, i, bf); lnbf[i] = ldin(lnb, i, bf); }

    // phase 0: 2-way split-K combine -> attnT
    int b_ = (int)(tok0 >> 12);
    int s_ = ((int)tok0 & 4095) >> 10;
    int tc0 = (int)tok0 & 1023;
    for (int idx = tid; idx < 32 * (ATS - DR); idx += 256) {
        int t = idx / (ATS - DR), f = idx % (ATS - DR);
        attnT[t * ATS + DR + f] = 0;
    }
    {
        int t = tid >> 3, h = tid & 7;
        const float* p1 = g_part + (((size_t)(b_ * NH + h)) * SPLIT + s_) * (size_t)(CHUNK * 20)
                        + (size_t)(tc0 + t) * 20;
        const size_t SL = (size_t)32 * SPLIT * CHUNK * 20;
        f32x4 a0 = {0,0,0,0}, a1 = {0,0,0,0}, a2 = {0,0,0,0}, a3 = {0,0,0,0}, a4 = {0,0,0,0};
        #pragma unroll
        for (int sl = 0; sl < NKSL; ++sl) {
            const float* p = p1 + sl * SL;
            a0 += *(const f32x4*)p;
            a1 += *(const f32x4*)(p + 4);
            a2 += *(const f32x4*)(p + 8);
            a3 += *(const f32x4*)(p + 12);
            a4 += *(const f32x4*)(p + 16);
        }
        float inv = 1.f / a4[2];
        u16* dst = attnT + t * ATS + h * HD;
        #pragma unroll
        for (int d = 0; d < 4; ++d) {
            dst[d]      = f2bits(a0[d] * inv);
            dst[4 + d]  = f2bits(a1[d] * inv);
            dst[8 + d]  = f2bits(a2[d] * inv);
            dst[12 + d] = f2bits(a3[d] * inv);
        }
        dst[16] = f2bits(a4[0] * inv);
        dst[17] = f2bits(a4[1] * inv);
    }
    __syncthreads();

    // phase A: proj + residual -> t1f (LDS only)
    {
        bf16x8 areg0[5], areg1[5];
        const u16* a0 = attnT + l15 * ATS + quad * 8;
        const u16* a1 = attnT + (16 + l15) * ATS + quad * 8;
        #pragma unroll
        for (int ks = 0; ks < 5; ++ks) {
            areg0[ks] = *(const bf16x8*)(a0 + ks * 32);
            areg1[ks] = *(const bf16x8*)(a1 + ks * 32);
        }
        const int tab[5] = {0, 5, 10, 14, 18};
        for (int nt = tab[w]; nt < tab[w + 1]; ++nt) {
            f32x4 acc0 = {0.f, 0.f, 0.f, 0.f}, acc1 = {0.f, 0.f, 0.f, 0.f};
            const u16* bbase = g_pw + (size_t)(nt * 16 + l15) * ASTR + quad * 8;
            #pragma unroll
            for (int ks = 0; ks < 5; ++ks) {
                bf16x8 bfr = *(const bf16x8*)(bbase + ks * 32);
                acc0 = __builtin_amdgcn_mfma_f32_16x16x32_bf16(areg0[ks], bfr, acc0, 0, 0, 0);
                acc1 = __builtin_amdgcn_mfma_f32_16x16x32_bf16(areg1[ks], bfr, acc1, 0, 0, 0);
            }
            int o = nt * 16 + l15;
            float bias = ldin(proj_b, o, bf);
            #pragma unroll
            for (int r = 0; r < 4; ++r) {
                t1f[(quad * 4 + r) * 296 + o] =
                    f2bits(bits2f(g_t0[(tok0 + quad * 4 + r) * D + o]) + acc0[r] + bias);
                t1f[(16 + quad * 4 + r) * 296 + o] =
                    f2bits(bits2f(g_t0[(tok0 + 16 + quad * 4 + r) * D + o]) + acc1[r] + bias);
            }
        }
    }
    __syncthreads();
    {   // phase B: LN2 stats
        int tt = tid >> 3, p = tid & 7;
        const u32* src = (const u32*)&t1f[tt * 296 + p * 36];
        float s = 0.f, q = 0.f;
        #pragma unroll
        for (int j = 0; j < 18; ++j) {
            u32 v = src[j];
            float a = bits2f((u16)(v & 0xFFFF)), b = bits2f((u16)(v >> 16));
            s += a + b; q += a * a + b * b;
        }
        #pragma unroll
        for (int o = 1; o < 8; o <<= 1) { s += __shfl_xor(s, o); q += __shfl_xor(q, o); }
        if (p == 0) {
            float mu = s / D;
            smu[tt] = mu;
            srs[tt] = rsqrtf(q / D - mu * mu + EPS_);
        }
    }
    __syncthreads();
    for (int idx = tid; idx < 32 * 144; idx += 256) {   // phase C: normalize
        int t = idx / 144, dw = idx % 144;
        int f = 2 * dw;
        u32 v = *(const u32*)&t1f[t * 296 + f];
        float mu = smu[t], rs = srs[t];
        float a = (bits2f((u16)(v & 0xFFFF)) - mu) * rs * lnwf[f] + lnbf[f];
        float b = (bits2f((u16)(v >> 16)) - mu) * rs * lnwf[f + 1] + lnbf[f + 1];
        *(u32*)&xln[t * 296 + f] = (u32)f2bits(a) | ((u32)f2bits(b) << 16);
    }
    __syncthreads();
    {   // phase D: fc1 + relu -> hbuf (LDS)
        bf16x8 areg0[9], areg1[9];
        const u16* a0 = xln + l15 * 296 + quad * 8;
        const u16* a1 = xln + (16 + l15) * 296 + quad * 8;
        #pragma unroll
        for (int ks = 0; ks < 9; ++ks) {
            areg0[ks] = *(const bf16x8*)(a0 + ks * 32);
            areg1[ks] = *(const bf16x8*)(a1 + ks * 32);
        }
        const int tab2[5] = {0, 2, 4, 5, 6};
        for (int nt = tab2[w]; nt < tab2[w + 1]; ++nt) {
            f32x4 acc0 = {0.f, 0.f, 0.f, 0.f}, acc1 = {0.f, 0.f, 0.f, 0.f};
            const u16* bbase = g_f1w + (size_t)(nt * 16 + l15) * D + quad * 8;
            #pragma unroll
            for (int ks = 0; ks < 9; ++ks) {
                bf16x8 bfr = *(const bf16x8*)(bbase + ks * 32);
                acc0 = __builtin_amdgcn_mfma_f32_16x16x32_bf16(areg0[ks], bfr, acc0, 0, 0, 0);
                acc1 = __builtin_amdgcn_mfma_f32_16x16x32_bf16(areg1[ks], bfr, acc1, 0, 0, 0);
            }
            int o = nt * 16 + l15;
            float bias = (o < DH) ? ldin(fc1_b, o, bf) : 0.f;
            #pragma unroll
            for (int r = 0; r < 4; ++r) {
                hbuf[(quad * 4 + r) * HSTR + o] = f2bits(fmaxf(acc0[r] + bias, 0.f));
                hbuf[(16 + quad * 4 + r) * HSTR + o] = f2bits(fmaxf(acc1[r] + bias, 0.f));
            }
        }
    }
    __syncthreads();
    {   // phase E: fc2 + residual -> t2 bf16, staged in xln
        bf16x8 areg0[3], areg1[3];
        const u16* a0 = hbuf + l15 * HSTR + quad * 8;
        const u16* a1 = hbuf + (16 + l15) * HSTR + quad * 8;
        #pragma unroll
        for (int ks = 0; ks < 3; ++ks) {
            areg0[ks] = *(const bf16x8*)(a0 + ks * 32);
            areg1[ks] = *(const bf16x8*)(a1 + ks * 32);
        }
        const int tab[5] = {0, 5, 10, 14, 18};
        for (int nt = tab[w]; nt < tab[w + 1]; ++nt) {
            f32x4 acc0 = {0.f, 0.f, 0.f, 0.f}, acc1 = {0.f, 0.f, 0.f, 0.f};
            const u16* bbase = g_f2w + (size_t)(nt * 16 + l15) * HSTR + quad * 8;
            #pragma unroll
            for (int ks = 0; ks < 3; ++ks) {
                bf16x8 bfr = *(const bf16x8*)(bbase + ks * 32);
                acc0 = __builtin_amdgcn_mfma_f32_16x16x32_bf16(areg0[ks], bfr, acc0, 0, 0, 0);
                acc1 = __builtin_amdgcn_mfma_f32_16x16x32_bf16(areg1[ks], bfr, acc1, 0, 0, 0);
            }
            int o = nt * 16 + l15;
            float bias = ldin(fc2_b, o, bf);
            #pragma unroll
            for (int r = 0; r < 4; ++r) {
                xln[(quad * 4 + r) * 296 + o] =
                    f2bits(bits2f(t1f[(quad * 4 + r) * 296 + o]) + acc0[r] + bias);
                xln[(16 + quad * 4 + r) * 296 + o] =
                    f2bits(bits2f(t1f[(16 + quad * 4 + r) * 296 + o]) + acc1[r] + bias);
            }
        }
    }
    __syncthreads();
    {   // transposed u32-packed store to g_t2b
        int n0 = (int)(tok0 & 4095);
        for (int idx = tid; idx < D * 16; idx += 256) {
            int o = idx >> 4, tp = idx & 15;
            u32 v = (u32)xln[(2 * tp) * 296 + o] | ((u32)xln[(2 * tp + 1) * 296 + o] << 16);
            *(u32*)&g_t2b[((size_t)b_ * D + o) * NN + n0 + 2 * tp] = v;
        }
    }
}

// ---- fold -> out
__global__ void k_fold(void* __restrict__ out) {
    int bf = g_flag;
    int idx = blockIdx.x * blockDim.x + threadIdx.x;
    if (idx >= BB * CCH * HH * WW) return;
    int xx = idx % WW;
    int y = (idx / WW) % HH;
    int c = (idx / (WW * HH)) % CCH;
    int b = idx / (WW * HH * CCH);
    const u16* base = g_t2b + ((size_t)b * D + c * 9) * NN;
    float s = 0.f;
    #pragma unroll
    for (int i = 0; i < 3; ++i) {
        int sy = y + 1 - i;
        if (sy < 0 || sy >= HH) continue;
        #pragma unroll
        for (int j = 0; j < 3; ++j) {
            int sx = xx + 1 - j;
            if (sx < 0 || sx >= WW) continue;
            s += bits2f(base[(size_t)(i * 3 + j) * NN + sy * WW + sx]);
        }
    }
    if (bf) ((bf16*)out)[idx] = __float2bfloat16(s);
    else    ((float*)out)[idx] = s;
}

extern "C" void kernel_launch(void* const* d_in, const int* in_sizes, int n_in,
                              void* d_out, int out_size, void* d_ws, size_t ws_size,
                              hipStream_t stream) {
    const void* x        = d_in[0];
    const void* ln1_w    = d_in[1];
    const void* ln1_b    = d_in[2];
    const void* reduce_w = d_in[3];
    const void* qkv_w    = d_in[4];
    const void* proj_w   = d_in[5];
    const void* proj_b   = d_in[6];
    const void* ln2_w    = d_in[7];
    const void* ln2_b    = d_in[8];
    const void* fc1_w    = d_in[9];
    const void* fc1_b    = d_in[10];
    const void* fc2_w    = d_in[11];
    const void* fc2_b    = d_in[12];

    k_prep     <<<DQ + RSB + PATCHB, 256, 0, stream>>>(x, qkv_w, reduce_w, proj_w, fc1_w, fc2_w);
    k_ln_qkv   <<<BB * NN / 32, 256, 0, stream>>>(ln1_w, ln1_b);
    k_attn     <<<NKSL * BB * NH * SPLIT * 8, 128, 0, stream>>>();
    k_proj_mlp <<<BB * NN / 32, 256, 0, stream>>>(proj_b, ln2_w, ln2_b, fc1_b, fc2_b);
    k_fold     <<<(BB * CCH * HH * WW + 255) / 256, 256, 0, stream>>>(d_out);
}

// Round 7
// 182.187 us; speedup vs baseline: 1.0720x; 1.0316x over previous
//
#include <hip/hip_runtime.h>
#include <hip/hip_bf16.h>

typedef __hip_bfloat16 bf16;
typedef unsigned short u16;
typedef unsigned int u32;
typedef __attribute__((ext_vector_type(8))) short bf16x8;
typedef __attribute__((ext_vector_type(4))) float f32x4;

#define BB 4
#define CCH 32
#define HH 64
#define WW 64
#define NN 4096
#define D 288
#define DR 144
#define DQ 432
#define NH 8
#define HD 18
#define SPLIT 4
#define CHUNK 1024
#define DH 72
#define SCALE_ 0.16666666666666666f
#define QSCALE 0.24044917348149343f   // SCALE_ * log2(e)
#define EPS_ 1e-5f
#define ASTR 160
#define ATS 168
#define HSTR 96

__device__ __attribute__((aligned(16))) u16 g_Wcb[DQ * D];
__device__ __attribute__((aligned(16))) u16 g_pw[D * ASTR];
__device__ __attribute__((aligned(16))) u16 g_f1w[HSTR * D];
__device__ __attribute__((aligned(16))) u16 g_f2w[D * HSTR];
__device__ __attribute__((aligned(16))) u16 g_q[(size_t)BB * NH * NN * 32];
__device__ __attribute__((aligned(16))) u16 g_k[(size_t)BB * NH * NN * 32];
__device__ __attribute__((aligned(16))) u16 g_vt[(size_t)BB * NH * SPLIT * 32 * CHUNK];
__device__ __attribute__((aligned(16))) u16 g_attn[(size_t)BB * NN * 144];  // final attn out, bf16
__device__ __attribute__((aligned(16))) u16 g_t0[(size_t)BB * NN * D];
__device__ __attribute__((aligned(16))) u16 g_t2b[(size_t)BB * D * NN];
__device__ int   g_flag;

__device__ __forceinline__ float b2f(bf16 v) { return __bfloat162float(v); }
__device__ __forceinline__ float bits2f(u16 u) { return __uint_as_float(((u32)u) << 16); }
__device__ __forceinline__ u16 f2bits(float f) {
    u32 u = __float_as_uint(f);
    return (u16)((u + 0x7FFF + ((u >> 16) & 1)) >> 16);
}
__device__ __forceinline__ float ldin(const void* p, size_t i, int isbf) {
    return isbf ? b2f(((const bf16*)p)[i]) : ((const float*)p)[i];
}
// pack exp2(e0), exp2(e1) as two truncated bf16 into one u32 (e0 = low half).
// raw v_exp_f32 (no OCML denorm-range fixup): S values are bounded (|S| << 126).
__device__ __forceinline__ u32 packexp(float e0, float e1) {
    float p0 = __builtin_amdgcn_exp2f(e0);
    float p1 = __builtin_amdgcn_exp2f(e1);
    return __builtin_amdgcn_perm(__float_as_uint(p1), __float_as_uint(p0), 0x07060302u);
}

#define RS  (D * ASTR + HSTR * D + D * HSTR)
#define RS2 (RS + BB * NH * SPLIT * CHUNK)
#define RSB ((RS2 + 255) / 256)
#define PATCHB (BB * HH)

// ---- prep: dtype detect + Wc GEMM + weight staging + vt ones row + patch extract
__global__ void k_prep(const void* __restrict__ x, const void* __restrict__ qkv_w,
                       const void* __restrict__ reduce_w, const void* __restrict__ proj_w,
                       const void* __restrict__ fc1_w, const void* __restrict__ fc2_w) {
    __shared__ int cnt4[4];
    __shared__ float qw[DR];
    __shared__ float slab[32 * 3 * 66];
    int tid = threadIdx.x;
    {
        const u16* u = (const u16*)x;
        int c = 0;
        for (int i = tid; i < 2048; i += 256) c += (((u[i] >> 7) & 0xFF) >= 0x90);
        for (int o = 32; o; o >>= 1) c += __shfl_xor(c, o);
        if ((tid & 63) == 0) cnt4[tid >> 6] = c;
    }
    __syncthreads();
    int bf = (cnt4[0] + cnt4[1] + cnt4[2] + cnt4[3]) < 32;
    if (tid == 0 && blockIdx.x == 0) g_flag = bf;

    int bid = blockIdx.x;
    if (bid < DQ) {
        int o = bid;
        if (tid < DR) qw[tid] = ldin(qkv_w, (size_t)o * DR + tid, bf);
        __syncthreads();
        for (int col = tid; col < D; col += 256) {
            float s0 = 0.f, s1 = 0.f;
            #pragma unroll 4
            for (int j = 0; j < DR; j += 2) {
                s0 += qw[j] * ldin(reduce_w, (size_t)j * D + col, bf);
                s1 += qw[j + 1] * ldin(reduce_w, (size_t)(j + 1) * D + col, bf);
            }
            g_Wcb[(size_t)o * D + col] = f2bits(s0 + s1);
        }
    } else if (bid < DQ + RSB) {
        int idx = (bid - DQ) * 256 + tid;
        if (idx < D * ASTR) {
            int o = idx / ASTR, j = idx % ASTR;
            g_pw[idx] = (j < DR) ? f2bits(ldin(proj_w, (size_t)o * DR + j, bf)) : (u16)0;
        } else if (idx < D * ASTR + HSTR * D) {
            int t = idx - D * ASTR;
            int o = t / D;
            g_f1w[t] = (o < DH) ? f2bits(ldin(fc1_w, (size_t)t, bf)) : (u16)0;
        } else if (idx < RS) {
            int t = idx - D * ASTR - HSTR * D;
            int o = t / HSTR, j = t % HSTR;
            g_f2w[t] = (j < DH) ? f2bits(ldin(fc2_w, (size_t)o * DH + j, bf)) : (u16)0;
        } else if (idx < RS2) {
            int t = idx - RS;
            int bhs = t >> 10, n = t & 1023;
            g_vt[((size_t)bhs * 32 + 18) * CHUNK + n] = 0x3F80;  // bf16 1.0
        }
    } else {
        int pb = bid - DQ - RSB;
        int b = pb >> 6, y = pb & 63;
        for (int idx = tid; idx < 32 * 3 * 66; idx += 256) {
            int c = idx / 198, rem = idx % 198;
            int ki = rem / 66, col = rem % 66 - 1;
            int sy = y + ki - 1;
            float v = 0.f;
            if (col >= 0 && col < 64 && sy >= 0 && sy < 64)
                v = ldin(x, ((size_t)(b * CCH + c) * HH + sy) * WW + col, bf);
            slab[idx] = v;
        }
        __syncthreads();
        size_t obase = ((size_t)b * NN + y * 64) * D;
        for (int idx = tid; idx < 64 * D; idx += 256) {
            int t = idx / D, f = idx % D;
            int c = f / 9, k = f % 9, ki = k / 3, kj = k % 3;
            g_t0[obase + idx] = f2bits(slab[c * 198 + ki * 66 + t + kj]);
        }
    }
}

// ---- LN1 + qkv GEMM; block = 32 tokens, dual A-tiles per B-load
__global__ void k_ln_qkv(const void* __restrict__ lnw, const void* __restrict__ lnb) {
    __shared__ __attribute__((aligned(16))) u16 xln[32 * 296];
    __shared__ float lnwf[D], lnbf[D];
    __shared__ float smu[32], srs[32];
    __shared__ u16 buf[3][144][32];
    int bf = g_flag;
    int tid = threadIdx.x;
    size_t tok0 = (size_t)blockIdx.x * 32;
    for (int i = tid; i < D; i += 256) { lnwf[i] = ldin(lnw, i, bf); lnbf[i] = ldin(lnb, i, bf); }
    {
        int tt = tid >> 3, p = tid & 7;
        const u32* pr = (const u32*)(g_t0 + (tok0 + tt) * D + p * 36);
        float s = 0.f, q = 0.f;
        #pragma unroll
        for (int j = 0; j < 18; ++j) {
            u32 v = pr[j];
            float a = bits2f((u16)(v & 0xFFFF)), b = bits2f((u16)(v >> 16));
            s += a + b; q += a * a + b * b;
        }
        #pragma unroll
        for (int o = 1; o < 8; o <<= 1) { s += __shfl_xor(s, o); q += __shfl_xor(q, o); }
        if (p == 0) {
            float mu = s / D;
            smu[tt] = mu;
            srs[tt] = rsqrtf(q / D - mu * mu + EPS_);
        }
    }
    __syncthreads();
    for (int idx = tid; idx < 32 * 144; idx += 256) {
        int t = idx / 144, dw = idx % 144;
        u32 v = *(const u32*)(g_t0 + (tok0 + t) * D + 2 * dw);
        float mu = smu[t], rs = srs[t];
        int f = 2 * dw;
        float a = (bits2f((u16)(v & 0xFFFF)) - mu) * rs * lnwf[f] + lnbf[f];
        float b = (bits2f((u16)(v >> 16)) - mu) * rs * lnwf[f + 1] + lnbf[f + 1];
        *(u32*)&xln[t * 296 + f] = (u32)f2bits(a) | ((u32)f2bits(b) << 16);
    }
    __syncthreads();
    int w = tid >> 6, lane = tid & 63, quad = lane >> 4, l15 = lane & 15;
    bf16x8 areg0[9], areg1[9];
    {
        const u16* a0 = xln + l15 * 296 + quad * 8;
        const u16* a1 = xln + (16 + l15) * 296 + quad * 8;
        #pragma unroll
        for (int ks = 0; ks < 9; ++ks) {
            areg0[ks] = *(const bf16x8*)(a0 + ks * 32);
            areg1[ks] = *(const bf16x8*)(a1 + ks * 32);
        }
    }
    int nt0 = w * 7, nt1 = (nt0 + 7 > 27) ? 27 : nt0 + 7;
    for (int nt = nt0; nt < nt1; ++nt) {
        f32x4 acc0 = {0.f, 0.f, 0.f, 0.f}, acc1 = {0.f, 0.f, 0.f, 0.f};
        const u16* bbase = g_Wcb + (size_t)(nt * 16 + l15) * D + quad * 8;
        #pragma unroll
        for (int ks = 0; ks < 9; ++ks) {
            bf16x8 bfr = *(const bf16x8*)(bbase + ks * 32);
            acc0 = __builtin_amdgcn_mfma_f32_16x16x32_bf16(areg0[ks], bfr, acc0, 0, 0, 0);
            acc1 = __builtin_amdgcn_mfma_f32_16x16x32_bf16(areg1[ks], bfr, acc1, 0, 0, 0);
        }
        int o = nt * 16 + l15;
        int which = o / DR, rem = o % DR;
        #pragma unroll
        for (int r = 0; r < 4; ++r) {
            buf[which][rem][quad * 4 + r] = f2bits(which == 0 ? acc0[r] * QSCALE : acc0[r]);
            buf[which][rem][16 + quad * 4 + r] = f2bits(which == 0 ? acc1[r] * QSCALE : acc1[r]);
        }
    }
    __syncthreads();
    {
        int b_ = (int)(tok0 >> 12);
        int n0 = (int)(tok0 & 4095);
        int sIdx = n0 >> 10, nc = n0 & 1023;
        for (int idx = tid; idx < 2 * 8 * 32 * 9; idx += 256) {
            int which = idx / 2304;
            int r2 = idx - which * 2304;
            int h = r2 / 288, r3 = r2 % 288, t = r3 / 9, dw = r3 % 9;
            u32 lo = buf[which][h * 18 + 2 * dw][t];
            u32 hi = buf[which][h * 18 + 2 * dw + 1][t];
            u16* dst = (which ? g_k : g_q) + ((size_t)(b_ * NH + h) * NN + n0 + t) * 32 + 2 * dw;
            *(u32*)dst = lo | (hi << 16);
        }
        // V^T store with the within-32 key permutation matching the register-resident
        // P fragment layout of the swapped-QK^T attention:
        //   pos(k) = 8*((k>>2)&3) + 4*(k>>4) + (k&3)   (bijection on [0,32))
        for (int idx = tid; idx < 144 * 16; idx += 256) {
            int rem = idx >> 4, tp = idx & 15;
            int hh = rem / HD, dd = rem % HD;
            u32 lo = buf[2][rem][2 * tp];
            u32 hi = buf[2][rem][2 * tp + 1];
            int k2 = 2 * tp;
            int pos = 8 * ((k2 >> 2) & 3) + 4 * (k2 >> 4) + (k2 & 3);
            size_t voff = (((size_t)(b_ * NH + hh) * SPLIT + sIdx) * 32 + dd) * CHUNK + nc + pos;
            *(u32*)&g_vt[voff] = lo | (hi << 16);
        }
    }
}

// ---- MFMA flash attention, NO split-K, LDS-free, K-prefetch software pipeline.
//      Each block walks all 1024 keys (16 pipelined 64-key steps) — prologue fully
//      amortized — and normalizes in-register at the end (denominator = ones-row of
//      V' at l15==2 of accB, broadcast via shfl), storing final bf16 attn output.
//      This removes the 21 MB f32 partial round trip entirely.
//      launch_bounds(128,4): ~100-120 regs live incl. K double-buffer; (128,8) spills.
__global__ __launch_bounds__(128, 4) void k_attn() {
    int bid = blockIdx.x;                // 0..1023
    int chunk = bid & 127;
    int qblk = bid >> 7;                 // 0..7
    int s = chunk & 3, bh = chunk >> 2;  // bh = b*NH+h
    int tid = threadIdx.x;
    int w = tid >> 6, lane = tid & 63, quad = lane >> 4, l15 = lane & 15;

    size_t rowbase = (size_t)bh * NN + s * CHUNK;
    size_t vtbase = ((size_t)bh * SPLIT + s) * 32 * CHUNK;
    const u16* kbase = g_k + rowbase * 32 + quad * 8;
    const u16* vbase = g_vt + vtbase + quad * 8;

    int qbase = qblk * 128 + w * 64;
    bf16x8 qf[4];
    #pragma unroll
    for (int t = 0; t < 4; ++t)
        qf[t] = *(const bf16x8*)(g_q + (rowbase + qbase + t * 16 + l15) * 32 + quad * 8);

    f32x4 accA[4], accB[4];
    #pragma unroll
    for (int t = 0; t < 4; ++t) {
        accA[t] = (f32x4){0.f, 0.f, 0.f, 0.f};
        accB[t] = (f32x4){0.f, 0.f, 0.f, 0.f};
    }

    auto loadK = [&](bf16x8 (&dst)[4], int kt) {
        dst[0] = *(const bf16x8*)(kbase + (size_t)(kt + l15) * 32);
        dst[1] = *(const bf16x8*)(kbase + (size_t)(kt + 16 + l15) * 32);
        dst[2] = *(const bf16x8*)(kbase + (size_t)(kt + 32 + l15) * 32);
        dst[3] = *(const bf16x8*)(kbase + (size_t)(kt + 48 + l15) * 32);
    };
    // one 64-key step: V loads for this step issue first (hidden under QK+exp),
    // then the NEXT step's K loads (prefetch), then compute.
    auto body = [&](bf16x8 (&kc)[4], bf16x8 (&kn)[4], int kt, bool pf) {
        bf16x8 vA0 = *(const bf16x8*)(vbase + (size_t)l15 * CHUNK + kt);
        bf16x8 vB0 = *(const bf16x8*)(vbase + (size_t)(16 + l15) * CHUNK + kt);
        bf16x8 vA1 = *(const bf16x8*)(vbase + (size_t)l15 * CHUNK + kt + 32);
        bf16x8 vB1 = *(const bf16x8*)(vbase + (size_t)(16 + l15) * CHUNK + kt + 32);
        if (pf) loadK(kn, kt + 64);
        f32x4 z = {0.f, 0.f, 0.f, 0.f};
        #pragma unroll
        for (int t = 0; t < 4; ++t) {
            __builtin_amdgcn_s_setprio(1);
            f32x4 S0 = __builtin_amdgcn_mfma_f32_16x16x32_bf16(kc[0], qf[t], z, 0, 0, 0);
            f32x4 S1 = __builtin_amdgcn_mfma_f32_16x16x32_bf16(kc[1], qf[t], z, 0, 0, 0);
            f32x4 S2 = __builtin_amdgcn_mfma_f32_16x16x32_bf16(kc[2], qf[t], z, 0, 0, 0);
            f32x4 S3 = __builtin_amdgcn_mfma_f32_16x16x32_bf16(kc[3], qf[t], z, 0, 0, 0);
            __builtin_amdgcn_s_setprio(0);
            union { u32 u[4]; bf16x8 v; } pa0, pa1;
            pa0.u[0] = packexp(S0[0], S0[1]);
            pa0.u[1] = packexp(S0[2], S0[3]);
            pa0.u[2] = packexp(S1[0], S1[1]);
            pa0.u[3] = packexp(S1[2], S1[3]);
            pa1.u[0] = packexp(S2[0], S2[1]);
            pa1.u[1] = packexp(S2[2], S2[3]);
            pa1.u[2] = packexp(S3[0], S3[1]);
            pa1.u[3] = packexp(S3[2], S3[3]);
            __builtin_amdgcn_s_setprio(1);
            accA[t] = __builtin_amdgcn_mfma_f32_16x16x32_bf16(pa0.v, vA0, accA[t], 0, 0, 0);
            accB[t] = __builtin_amdgcn_mfma_f32_16x16x32_bf16(pa0.v, vB0, accB[t], 0, 0, 0);
            accA[t] = __builtin_amdgcn_mfma_f32_16x16x32_bf16(pa1.v, vA1, accA[t], 0, 0, 0);
            accB[t] = __builtin_amdgcn_mfma_f32_16x16x32_bf16(pa1.v, vB1, accB[t], 0, 0, 0);
            __builtin_amdgcn_s_setprio(0);
        }
    };

    bf16x8 ka[4], kb[4];
    loadK(ka, 0);
    #pragma unroll
    for (int it = 0; it < 8; ++it) {
        body(ka, kb, it * 128, true);
        body(kb, ka, it * 128 + 64, it < 7);
    }

    // epilogue: normalize + direct bf16 store. accA cols = dims 0..15 (l15),
    // accB cols 0,1 = dims 16,17; accB col 2 = ones-row denominator.
    u16* abase = g_attn + ((size_t)(bh >> 3) * NN + s * CHUNK) * 144 + (bh & 7) * HD;
    int srcl = (lane & 48) | 2;
    #pragma unroll
    for (int t = 0; t < 4; ++t) {
        #pragma unroll
        for (int r = 0; r < 4; ++r) {
            float den = __shfl(accB[t][r], srcl);
            float inv = __builtin_amdgcn_rcpf(den);
            int tc = qbase + t * 16 + quad * 4 + r;
            u16* dst = abase + (size_t)tc * 144;
            dst[l15] = f2bits(accA[t][r] * inv);
            if (l15 < 2) dst[16 + l15] = f2bits(accB[t][r] * inv);
        }
    }
}

// ---- fused proj + residual + LN2 + fc1 + relu + fc2 + residual
__global__ void k_proj_mlp(const void* __restrict__ proj_b, const void* __restrict__ lnw,
                           const void* __restrict__ lnb, const void* __restrict__ fc1_b,
                           const void* __restrict__ fc2_b) {
    __shared__ __attribute__((aligned(16))) u16 t1f[32 * 296];   // bf16 t1 tile
    __shared__ __attribute__((aligned(16))) u16 xln[32 * 296];   // LN2 out, reused for t2 stage
    __shared__ __attribute__((aligned(16))) u16 attnT[32 * ATS];
    __shared__ __attribute__((aligned(16))) u16 hbuf[32 * HSTR];
    __shared__ float lnwf[D], lnbf[D];
    __shared__ float smu[32], srs[32];
    int bf = g_flag;
    int tid = threadIdx.x;
    size_t tok0 = (size_t)blockIdx.x * 32;
    int w = tid >> 6, lane = tid & 63, quad = lane >> 4, l15 = lane & 15;
    for (int i = tid; i < D; i += 256) { lnwf[i] = ldin(lnw, i, bf); lnbf[i] = ldin(lnb, i, bf); }

    // phase 0: stage final attn tile (bf16, already normalized by k_attn) -> attnT
    int b_ = (int)(tok0 >> 12);
    int n0 = (int)(tok0 & 4095);
    for (int idx = tid; idx < 32 * (ATS - DR); idx += 256) {
        int t = idx / (ATS - DR), f = idx % (ATS - DR);
        attnT[t * ATS + DR + f] = 0;
    }
    {
        const u16* src = g_attn + ((size_t)b_ * NN + n0) * 144;
        for (int idx = tid; idx < 32 * 72; idx += 256) {
            int t = idx / 72, dw = idx % 72;
            *(u32*)&attnT[t * ATS + 2 * dw] = *(const u32*)&src[(size_t)t * 144 + 2 * dw];
        }
    }
    __syncthreads();

    // phase A: proj + residual -> t1f (LDS only)
    {
        bf16x8 areg0[5], areg1[5];
        const u16* a0 = attnT + l15 * ATS + quad * 8;
        const u16* a1 = attnT + (16 + l15) * ATS + quad * 8;
        #pragma unroll
        for (int ks = 0; ks < 5; ++ks) {
            areg0[ks] = *(const bf16x8*)(a0 + ks * 32);
            areg1[ks] = *(const bf16x8*)(a1 + ks * 32);
        }
        const int tab[5] = {0, 5, 10, 14, 18};
        for (int nt = tab[w]; nt < tab[w + 1]; ++nt) {
            f32x4 acc0 = {0.f, 0.f, 0.f, 0.f}, acc1 = {0.f, 0.f, 0.f, 0.f};
            const u16* bbase = g_pw + (size_t)(nt * 16 + l15) * ASTR + quad * 8;
            #pragma unroll
            for (int ks = 0; ks < 5; ++ks) {
                bf16x8 bfr = *(const bf16x8*)(bbase + ks * 32);
                acc0 = __builtin_amdgcn_mfma_f32_16x16x32_bf16(areg0[ks], bfr, acc0, 0, 0, 0);
                acc1 = __builtin_amdgcn_mfma_f32_16x16x32_bf16(areg1[ks], bfr, acc1, 0, 0, 0);
            }
            int o = nt * 16 + l15;
            float bias = ldin(proj_b, o, bf);
            #pragma unroll
            for (int r = 0; r < 4; ++r) {
                t1f[(quad * 4 + r) * 296 + o] =
                    f2bits(bits2f(g_t0[(tok0 + quad * 4 + r) * D + o]) + acc0[r] + bias);
                t1f[(16 + quad * 4 + r) * 296 + o] =
                    f2bits(bits2f(g_t0[(tok0 + 16 + quad * 4 + r) * D + o]) + acc1[r] + bias);
            }
        }
    }
    __syncthreads();
    {   // phase B: LN2 stats
        int tt = tid >> 3, p = tid & 7;
        const u32* src = (const u32*)&t1f[tt * 296 + p * 36];
        float s = 0.f, q = 0.f;
        #pragma unroll
        for (int j = 0; j < 18; ++j) {
            u32 v = src[j];
            float a = bits2f((u16)(v & 0xFFFF)), b = bits2f((u16)(v >> 16));
            s += a + b; q += a * a + b * b;
        }
        #pragma unroll
        for (int o = 1; o < 8; o <<= 1) { s += __shfl_xor(s, o); q += __shfl_xor(q, o); }
        if (p == 0) {
            float mu = s / D;
            smu[tt] = mu;
            srs[tt] = rsqrtf(q / D - mu * mu + EPS_);
        }
    }
    __syncthreads();
    for (int idx = tid; idx < 32 * 144; idx += 256) {   // phase C: normalize
        int t = idx / 144, dw = idx % 144;
        int f = 2 * dw;
        u32 v = *(const u32*)&t1f[t * 296 + f];
        float mu = smu[t], rs = srs[t];
        float a = (bits2f((u16)(v & 0xFFFF)) - mu) * rs * lnwf[f] + lnbf[f];
        float b = (bits2f((u16)(v >> 16)) - mu) * rs * lnwf[f + 1] + lnbf[f + 1];
        *(u32*)&xln[t * 296 + f] = (u32)f2bits(a) | ((u32)f2bits(b) << 16);
    }
    __syncthreads();
    {   // phase D: fc1 + relu -> hbuf (LDS)
        bf16x8 areg0[9], areg1[9];
        const u16* a0 = xln + l15 * 296 + quad * 8;
        const u16* a1 = xln + (16 + l15) * 296 + quad * 8;
        #pragma unroll
        for (int ks = 0; ks < 9; ++ks) {
            areg0[ks] = *(const bf16x8*)(a0 + ks * 32);
            areg1[ks] = *(const bf16x8*)(a1 + ks * 32);
        }
        const int tab2[5] = {0, 2, 4, 5, 6};
        for (int nt = tab2[w]; nt < tab2[w + 1]; ++nt) {
            f32x4 acc0 = {0.f, 0.f, 0.f, 0.f}, acc1 = {0.f, 0.f, 0.f, 0.f};
            const u16* bbase = g_f1w + (size_t)(nt * 16 + l15) * D + quad * 8;
            #pragma unroll
            for (int ks = 0; ks < 9; ++ks) {
                bf16x8 bfr = *(const bf16x8*)(bbase + ks * 32);
                acc0 = __builtin_amdgcn_mfma_f32_16x16x32_bf16(areg0[ks], bfr, acc0, 0, 0, 0);
                acc1 = __builtin_amdgcn_mfma_f32_16x16x32_bf16(areg1[ks], bfr, acc1, 0, 0, 0);
            }
            int o = nt * 16 + l15;
            float bias = (o < DH) ? ldin(fc1_b, o, bf) : 0.f;
            #pragma unroll
            for (int r = 0; r < 4; ++r) {
                hbuf[(quad * 4 + r) * HSTR + o] = f2bits(fmaxf(acc0[r] + bias, 0.f));
                hbuf[(16 + quad * 4 + r) * HSTR + o] = f2bits(fmaxf(acc1[r] + bias, 0.f));
            }
        }
    }
    __syncthreads();
    {   // phase E: fc2 + residual -> t2 bf16, staged in xln
        bf16x8 areg0[3], areg1[3];
        const u16* a0 = hbuf + l15 * HSTR + quad * 8;
        const u16* a1 = hbuf + (16 + l15) * HSTR + quad * 8;
        #pragma unroll
        for (int ks = 0; ks < 3; ++ks) {
            areg0[ks] = *(const bf16x8*)(a0 + ks * 32);
            areg1[ks] = *(const bf16x8*)(a1 + ks * 32);
        }
        const int tab[5] = {0, 5, 10, 14, 18};
        for (int nt = tab[w]; nt < tab[w + 1]; ++nt) {
            f32x4 acc0 = {0.f, 0.f, 0.f, 0.f}, acc1 = {0.f, 0.f, 0.f, 0.f};
            const u16* bbase = g_f2w + (size_t)(nt * 16 + l15) * HSTR + quad * 8;
            #pragma unroll
            for (int ks = 0; ks < 3; ++ks) {
                bf16x8 bfr = *(const bf16x8*)(bbase + ks * 32);
                acc0 = __builtin_amdgcn_mfma_f32_16x16x32_bf16(areg0[ks], bfr, acc0, 0, 0, 0);
                acc1 = __builtin_amdgcn_mfma_f32_16x16x32_bf16(areg1[ks], bfr, acc1, 0, 0, 0);
            }
            int o = nt * 16 + l15;
            float bias = ldin(fc2_b, o, bf);
            #pragma unroll
            for (int r = 0; r < 4; ++r) {
                xln[(quad * 4 + r) * 296 + o] =
                    f2bits(bits2f(t1f[(quad * 4 + r) * 296 + o]) + acc0[r] + bias);
                xln[(16 + quad * 4 + r) * 296 + o] =
                    f2bits(bits2f(t1f[(16 + quad * 4 + r) * 296 + o]) + acc1[r] + bias);
            }
        }
    }
    __syncthreads();
    {   // transposed u32-packed store to g_t2b
        for (int idx = tid; idx < D * 16; idx += 256) {
            int o = idx >> 4, tp = idx & 15;
            u32 v = (u32)xln[(2 * tp) * 296 + o] | ((u32)xln[(2 * tp + 1) * 296 + o] << 16);
            *(u32*)&g_t2b[((size_t)b_ * D + o) * NN + n0 + 2 * tp] = v;
        }
    }
}

// ---- fold -> out
__global__ void k_fold(void* __restrict__ out) {
    int bf = g_flag;
    int idx = blockIdx.x * blockDim.x + threadIdx.x;
    if (idx >= BB * CCH * HH * WW) return;
    int xx = idx % WW;
    int y = (idx / WW) % HH;
    int c = (idx / (WW * HH)) % CCH;
    int b = idx / (WW * HH * CCH);
    const u16* base = g_t2b + ((size_t)b * D + c * 9) * NN;
    float s = 0.f;
    #pragma unroll
    for (int i = 0; i < 3; ++i) {
        int sy = y + 1 - i;
        if (sy < 0 || sy >= HH) continue;
        #pragma unroll
        for (int j = 0; j < 3; ++j) {
            int sx = xx + 1 - j;
            if (sx < 0 || sx >= WW) continue;
            s += bits2f(base[(size_t)(i * 3 + j) * NN + sy * WW + sx]);
        }
    }
    if (bf) ((bf16*)out)[idx] = __float2bfloat16(s);
    else    ((float*)out)[idx] = s;
}

extern "C" void kernel_launch(void* const* d_in, const int* in_sizes, int n_in,
                              void* d_out, int out_size, void* d_ws, size_t ws_size,
                              hipStream_t stream) {
    const void* x        = d_in[0];
    const void* ln1_w    = d_in[1];
    const void* ln1_b    = d_in[2];
    const void* reduce_w = d_in[3];
    const void* qkv_w    = d_in[4];
    const void* proj_w   = d_in[5];
    const void* proj_b   = d_in[6];
    const void* ln2_w    = d_in[7];
    const void* ln2_b    = d_in[8];
    const void* fc1_w    = d_in[9];
    const void* fc1_b    = d_in[10];
    const void* fc2_w    = d_in[11];
    const void* fc2_b    = d_in[12];

    k_prep     <<<DQ + RSB + PATCHB, 256, 0, stream>>>(x, qkv_w, reduce_w, proj_w, fc1_w, fc2_w);
    k_ln_qkv   <<<BB * NN / 32, 256, 0, stream>>>(ln1_w, ln1_b);
    k_attn     <<<BB * NH * SPLIT * 8, 128, 0, stream>>>();
    k_proj_mlp <<<BB * NN / 32, 256, 0, stream>>>(proj_b, ln2_w, ln2_b, fc1_b, fc2_b);
    k_fold     <<<(BB * CCH * HH * WW + 255) / 256, 256, 0, stream>>>(d_out);
}